// Round 19
// baseline (185.728 us; speedup 1.0000x reference)
//
#include <hip/hip_runtime.h>
#include <hip/hip_bf16.h>

// ---------------- problem constants ----------------
#define N_NODES 10000
#define IN_DIM  512
#define OUT_DIM 128
#define NE      262144
#define K_DIM   10000
#define HT_S    10112          // padded hT stride (zeros in [10000,10112))

// ---------------- GEMM2 (adj @ h) tiling ----------------
#define BM 64
#define BN 128
#define BK 128
#define SPLITS 4
#define KSTEPS_TOTAL 79        // ceil(10000/128)
#define STEPS_PER_SPLIT 20     // 3*20 + 19 = 79

typedef __attribute__((ext_vector_type(8))) __bf16 bf16x8;
typedef __attribute__((ext_vector_type(4))) float  f32x4;
typedef _Float16 h16x2 __attribute__((ext_vector_type(2)));

// Native bf16 convert (RNE): pairs fold to v_cvt_pk_bf16_f32 (R18: −7us).
__device__ inline ushort f2bf(float f) {
    __hip_bfloat16 h = __float2bfloat16(f);
    return __builtin_bit_cast(ushort, h);
}
__device__ inline ushort f2h(float f) {
    _Float16 h = (_Float16)f;
    return __builtin_bit_cast(ushort, h);
}

// async global -> LDS, 16 bytes per lane (global_load_lds_dwordx4)
__device__ __forceinline__ void gl2lds16(const void* g, void* l) {
    __builtin_amdgcn_global_load_lds(
        (const __attribute__((address_space(1))) void*)g,
        (__attribute__((address_space(3))) void*)l, 16, 0, 0);
}

// ---------------- kernel 0: WT = W^T bf16, v = W2 @ w3[:128], hT pad zero ----
__global__ __launch_bounds__(256) void k_prep(const float* __restrict__ w,
                                              const float* __restrict__ w2,
                                              const float* __restrict__ w3,
                                              ushort* __restrict__ WT,
                                              float* __restrict__ v,
                                              ushort* __restrict__ hT) {
    const int t = threadIdx.x;
    for (int idx = blockIdx.x * 256 + t; idx < IN_DIM * OUT_DIM; idx += gridDim.x * 256) {
        int k = idx >> 7, n = idx & 127;
        WT[n * IN_DIM + k] = f2bf(w[idx]);
    }
    if (blockIdx.x == 0) {
        float s = 0.f;
        for (int j = 0; j < OUT_DIM; ++j) s += w2[t * OUT_DIM + j] * w3[j];
        v[t] = s;
    }
    if (blockIdx.x == 1) {
        for (int idx = t; idx < 128 * (HT_S - N_NODES); idx += 256) {
            int c = idx / (HT_S - N_NODES), r = idx % (HT_S - N_NODES);
            hT[(size_t)c * HT_S + N_NODES + r] = 0;
        }
    }
}

// ---------------- kernel 1: hT = (x @ W)^T bf16 (R11-proven) ----------------
__global__ __launch_bounds__(256) void k_xw(const float* __restrict__ x,
                                            const ushort* __restrict__ WT,
                                            ushort* __restrict__ hT) {
    const int tid = threadIdx.x, wave = tid >> 6, lane = tid & 63;
    const int lr = lane & 15, lg = lane >> 4;
    const int r0 = blockIdx.x * 16;       // 625 * 16 = 10000 exactly
    const int c0 = wave * 32;             // 4 waves x 32 cols
    const float* pA = x + (size_t)(r0 + lr) * IN_DIM;

    f32x4 acc[2];
#pragma unroll
    for (int nf = 0; nf < 2; ++nf) acc[nf] = (f32x4){0.f, 0.f, 0.f, 0.f};

#pragma unroll
    for (int st = 0; st < 8; ++st) {
        const int k0 = st * 64;
        bf16x8 abf[2];
#pragma unroll
        for (int kh = 0; kh < 2; ++kh) {
            float4 a0 = *(const float4*)(pA + k0 + kh * 32 + lg * 8);
            float4 a1 = *(const float4*)(pA + k0 + kh * 32 + lg * 8 + 4);
            ushort* ap = (ushort*)&abf[kh];
            ap[0] = f2bf(a0.x); ap[1] = f2bf(a0.y); ap[2] = f2bf(a0.z); ap[3] = f2bf(a0.w);
            ap[4] = f2bf(a1.x); ap[5] = f2bf(a1.y); ap[6] = f2bf(a1.z); ap[7] = f2bf(a1.w);
        }
#pragma unroll
        for (int kh = 0; kh < 2; ++kh)
#pragma unroll
            for (int nf = 0; nf < 2; ++nf) {
                bf16x8 bfv = *(const bf16x8*)(WT + (size_t)(c0 + nf * 16 + lr) * IN_DIM + k0 + kh * 32 + lg * 8);
                acc[nf] = __builtin_amdgcn_mfma_f32_16x16x32_bf16(abf[kh], bfv, acc[nf], 0, 0, 0);
            }
    }

    const int m0 = r0 + lg * 4;           // rows m0..m0+3, 4-aligned, < 10000
#pragma unroll
    for (int nf = 0; nf < 2; ++nf) {
        int c = c0 + nf * 16 + lr;
        ushort4 pk;
        pk.x = f2bf(acc[nf][0]); pk.y = f2bf(acc[nf][1]);
        pk.z = f2bf(acc[nf][2]); pk.w = f2bf(acc[nf][3]);
        *(ushort4*)(hT + (size_t)c * HT_S + m0) = pk;
    }
}

// ---------------- kernel 2: zp[split] = adj @ h, BK=128 (R18-proven) --------
// SPLITS 8->4: halves zp write traffic (41->20.5 MB); occupancy-insensitivity
// proven R3/R4/R6 (628 blocks = 2.45/CU is enough).
__global__ __launch_bounds__(256) void k_adj(const float* __restrict__ adj,
                                             const ushort* __restrict__ hT,
                                             float* __restrict__ zp) {
    __shared__ ushort Bs[BN * BK];        // 32 KB

    const int tid = threadIdx.x, wave = tid >> 6, lane = tid & 63;
    const int lr = lane & 15, lg = lane >> 4;
    const int m0 = blockIdx.x * BM;
    const int split = blockIdx.y;
    const int step0 = split * STEPS_PER_SPLIT;
    const int step1 = min(step0 + STEPS_PER_SPLIT, KSTEPS_TOTAL);

    // B staging descriptors (loop-invariant): 2048 chunks of 16B
    long  bbase[8];
    char* bldst[8];
#pragma unroll
    for (int q = 0; q < 8; ++q) {
        int c = tid + q * 256;
        int row = c >> 4, ch = c & 15;
        bbase[q] = (long)row * HT_S + (long)((ch ^ (row & 15)) * 8);
        bldst[q] = (char*)Bs + c * 16;
    }

    // A row pointer (clamped; out-of-range rows' outputs are discarded)
    const int arow = min(m0 + wave * 16 + lr, N_NODES - 1);
    const float* pA = adj + (size_t)arow * K_DIM;

    f32x4 acc[8];
#pragma unroll
    for (int nf = 0; nf < 8; ++nf) acc[nf] = (f32x4){0.f, 0.f, 0.f, 0.f};

    const char* Bb = (const char*)Bs;

    for (int st = step0; st < step1; ++st) {
        const int k0 = st * BK;

        // stage B via async DMA (32 KB / block / step, hT is L2-resident)
#pragma unroll
        for (int q = 0; q < 8; ++q)
            gl2lds16(hT + (bbase[q] + k0), bldst[q]);

        // A direct to registers: 8 independent dwordx4 (clamped so k-overrun
        // lanes read in-bounds; their products hit B=0 pad rows)
        float4 fa[4][2];
#pragma unroll
        for (int kh = 0; kh < 4; ++kh) {
            int kk = k0 + kh * 32 + lg * 8;
            int kc = (kk <= K_DIM - 8) ? kk : (K_DIM - 8);
            fa[kh][0] = *(const float4*)(pA + kc);
            fa[kh][1] = *(const float4*)(pA + kc + 4);
        }

        __syncthreads();   // B tile visible (vmcnt0 also covers A regs)

#pragma unroll
        for (int kh = 0; kh < 4; ++kh) {
            bf16x8 abf;
            ushort* ap = (ushort*)&abf;
            const float* f0 = (const float*)&fa[kh][0];
#pragma unroll
            for (int e = 0; e < 8; ++e) ap[e] = f2bf(f0[e]);
#pragma unroll
            for (int nf = 0; nf < 8; ++nf) {
                int brow = nf * 16 + lr;
                bf16x8 bv = *(const bf16x8*)(Bb + brow * 256 + (((kh * 4 + lg) ^ (brow & 15)) * 16));
                acc[nf] = __builtin_amdgcn_mfma_f32_16x16x32_bf16(abf, bv, acc[nf], 0, 0, 0);
            }
        }

        __syncthreads();   // all B reads done before next-step overwrite
    }

    // epilogue: write split-partial z
    float* out = zp + (size_t)split * N_NODES * OUT_DIM;
    const int orow = m0 + wave * 16 + lg * 4;
#pragma unroll
    for (int nf = 0; nf < 8; ++nf)
#pragma unroll
        for (int r = 0; r < 4; ++r) {
            int row = orow + r;
            if (row < N_NODES)
                out[(size_t)row * OUT_DIM + nf * 16 + lr] = acc[nf][r];
        }
}

// ---------------- kernel 3: reduce splits + per-node precompute --------------
// zh is f16 now (finer mantissa than bf16 for |z|~1e-2; enables pk_mul/fdot2).
__global__ __launch_bounds__(256) void k_node(const float* __restrict__ zp,
                                              const float* __restrict__ v,
                                              float* __restrict__ a,
                                              float* __restrict__ b,
                                              ushort* __restrict__ zh) {
    const int wave = threadIdx.x >> 6, lane = threadIdx.x & 63;
    const int i = blockIdx.x * 4 + wave;
    if (i >= N_NODES) return;
    const int k0 = lane, k1 = lane + 64;

    float z0 = 0.f, z1 = 0.f;
#pragma unroll
    for (int s = 0; s < SPLITS; ++s) {
        const float* row = zp + ((size_t)s * N_NODES + i) * OUT_DIM;
        z0 += row[k0];
        z1 += row[k1];
    }
    zh[(size_t)i * OUT_DIM + k0] = f2h(z0);
    zh[(size_t)i * OUT_DIM + k1] = f2h(z1);

    float ra = fmaxf(z0, 0.f) * v[k0] + fmaxf(z1, 0.f) * v[k1];
    float rb = fmaxf(z0, 0.f) * v[OUT_DIM + k0] + fmaxf(z1, 0.f) * v[OUT_DIM + k1];
#pragma unroll
    for (int off = 32; off; off >>= 1) {
        ra += __shfl_down(ra, off);
        rb += __shfl_down(rb, off);
    }
    if (lane == 0) { a[i] = ra; b[i] = rb; }
}

// ---------------- kernel 4: per-edge logit + sigmoid -------------------------
// Packed-f16 math: per 2 elems, v_pk_mul_f16 (w3*zi) + v_dot2_f32_f16 (*zj,
// f32 accum) = 2 inst vs 4 (shl+and+2fma). Single f16 table (2.5 MB, L2-fit).
// 4 edges/wave, 16 lanes x 8 elements per edge (R11-proven shape).
__global__ __launch_bounds__(256) void k_edge(const int* __restrict__ e_true,
                                              const int* __restrict__ e_false,
                                              const float* __restrict__ a,
                                              const float* __restrict__ b,
                                              const ushort* __restrict__ zh,
                                              const float* __restrict__ w3,
                                              float* __restrict__ out) {
    const int lane = threadIdx.x & 63;
    const int grp  = lane >> 4;            // 4 edge-slots per wave
    const int l16  = lane & 15;
    const int gw   = (blockIdx.x * blockDim.x + threadIdx.x) >> 6;
    const int nw   = (gridDim.x * blockDim.x) >> 6;

    // lane l16 owns k = 8*l16 .. 8*l16+7; w3b as packed f16 pairs
    h16x2 wh[4];
#pragma unroll
    for (int e = 0; e < 4; ++e) {
        float w0 = w3[OUT_DIM + l16 * 8 + 2 * e];
        float w1 = w3[OUT_DIM + l16 * 8 + 2 * e + 1];
        wh[e] = (h16x2){(_Float16)w0, (_Float16)w1};
    }

    for (int e4 = gw; e4 < (2 * NE) / 4; e4 += nw) {
        const int e = e4 * 4 + grp;
        int2 ij = (e < NE) ? ((const int2*)e_true)[e] : ((const int2*)e_false)[e - NE];
        const int i = ij.x, j = ij.y;

        uint4 zi4 = *(const uint4*)(zh + (size_t)i * OUT_DIM + l16 * 8);
        uint4 zj4 = *(const uint4*)(zh + (size_t)j * OUT_DIM + l16 * 8);
        const uint* zi = (const uint*)&zi4;
        const uint* zj = (const uint*)&zj4;

        float d = 0.f;
#pragma unroll
        for (int q = 0; q < 4; ++q) {
            h16x2 p = wh[q] * __builtin_bit_cast(h16x2, zi[q]);   // v_pk_mul_f16
            d = __builtin_amdgcn_fdot2(p, __builtin_bit_cast(h16x2, zj[q]), d, false);
        }

#pragma unroll
        for (int off = 8; off; off >>= 1) d += __shfl_xor(d, off, 64);
        if (l16 == 0) {
            float logit = a[i] + b[j] + d;
            out[e] = 1.0f / (1.0f + __expf(-logit));
        }
    }
}

// ---------------- launch ----------------
extern "C" void kernel_launch(void* const* d_in, const int* in_sizes, int n_in,
                              void* d_out, int out_size, void* d_ws, size_t ws_size,
                              hipStream_t stream) {
    const float* x      = (const float*)d_in[0];
    const float* adj    = (const float*)d_in[1];
    const float* w      = (const float*)d_in[2];
    const float* w2     = (const float*)d_in[3];
    const float* w3     = (const float*)d_in[4];
    const int* e_true   = (const int*)d_in[5];
    const int* e_false  = (const int*)d_in[6];
    float* out          = (float*)d_out;

    char* ws = (char*)d_ws;
    // workspace layout (bytes)
    ushort* hT  = (ushort*)(ws);                        //  2,588,672 (128 x 10112 bf16)
    float*  zp  = (float*)(ws + 2588672);               // 20,480,000 (4 x 10000 x 128 f32)
    float*  v   = (float*)(ws + 23068672);              //      1,024
    float*  a   = (float*)(ws + 23069696);              //     40,000
    float*  b   = (float*)(ws + 23109696);              //     40,000
    ushort* zh  = (ushort*)(ws + 23149696);             //  2,560,000 (f16)
    ushort* WT  = (ushort*)(ws + 25709696);             //    131,072  -> ~25.8 MB

    k_prep<<<64, 256, 0, stream>>>(w, w2, w3, WT, v, hT);
    k_xw<<<625, 256, 0, stream>>>(x, WT, hT);
    k_adj<<<dim3(157, SPLITS), 256, 0, stream>>>(adj, hT, zp);
    k_node<<<2500, 256, 0, stream>>>(zp, v, a, b, zh);
    k_edge<<<2048, 256, 0, stream>>>(e_true, e_false, a, b, zh, w3, out);
}

// Round 20
// 179.764 us; speedup vs baseline: 1.0332x; 1.0332x over previous
//
#include <hip/hip_runtime.h>
#include <hip/hip_bf16.h>

// ---------------- problem constants ----------------
#define N_NODES 10000
#define IN_DIM  512
#define OUT_DIM 128
#define NE      262144
#define K_DIM   10000
#define HT_S    10112          // padded hT stride (zeros in [10000,10112))

// ---------------- GEMM2 (adj @ h) tiling ----------------
#define BM 64
#define BN 128
#define BK 128
#define SPLITS 8
#define KSTEPS_TOTAL 79        // ceil(10000/128)
#define STEPS_PER_SPLIT 10     // 7*10 + 9 = 79

typedef __attribute__((ext_vector_type(8))) __bf16 bf16x8;
typedef __attribute__((ext_vector_type(4))) float  f32x4;

// Native bf16 convert (RNE): pairs fold to v_cvt_pk_bf16_f32 (R18: −7us).
__device__ inline ushort f2bf(float f) {
    __hip_bfloat16 h = __float2bfloat16(f);
    return __builtin_bit_cast(ushort, h);
}
__device__ inline float bflo(uint u) { return __uint_as_float(u << 16); }
__device__ inline float bfhi(uint u) { return __uint_as_float(u & 0xffff0000u); }

// async global -> LDS, 16 bytes per lane (global_load_lds_dwordx4)
__device__ __forceinline__ void gl2lds16(const void* g, void* l) {
    __builtin_amdgcn_global_load_lds(
        (const __attribute__((address_space(1))) void*)g,
        (__attribute__((address_space(3))) void*)l, 16, 0, 0);
}

// ---------------- kernel 0: WT = W^T bf16, v = W2 @ w3[:128], hT pad zero ----
__global__ __launch_bounds__(256) void k_prep(const float* __restrict__ w,
                                              const float* __restrict__ w2,
                                              const float* __restrict__ w3,
                                              ushort* __restrict__ WT,
                                              float* __restrict__ v,
                                              ushort* __restrict__ hT) {
    const int t = threadIdx.x;
    for (int idx = blockIdx.x * 256 + t; idx < IN_DIM * OUT_DIM; idx += gridDim.x * 256) {
        int k = idx >> 7, n = idx & 127;
        WT[n * IN_DIM + k] = f2bf(w[idx]);
    }
    if (blockIdx.x == 0) {
        float s = 0.f;
        for (int j = 0; j < OUT_DIM; ++j) s += w2[t * OUT_DIM + j] * w3[j];
        v[t] = s;
    }
    if (blockIdx.x == 1) {
        for (int idx = t; idx < 128 * (HT_S - N_NODES); idx += 256) {
            int c = idx / (HT_S - N_NODES), r = idx % (HT_S - N_NODES);
            hT[(size_t)c * HT_S + N_NODES + r] = 0;
        }
    }
}

// ---------------- kernel 1: hT = (x @ W)^T bf16 (R11-proven) ----------------
__global__ __launch_bounds__(256) void k_xw(const float* __restrict__ x,
                                            const ushort* __restrict__ WT,
                                            ushort* __restrict__ hT) {
    const int tid = threadIdx.x, wave = tid >> 6, lane = tid & 63;
    const int lr = lane & 15, lg = lane >> 4;
    const int r0 = blockIdx.x * 16;       // 625 * 16 = 10000 exactly
    const int c0 = wave * 32;             // 4 waves x 32 cols
    const float* pA = x + (size_t)(r0 + lr) * IN_DIM;

    f32x4 acc[2];
#pragma unroll
    for (int nf = 0; nf < 2; ++nf) acc[nf] = (f32x4){0.f, 0.f, 0.f, 0.f};

#pragma unroll
    for (int st = 0; st < 8; ++st) {
        const int k0 = st * 64;
        bf16x8 abf[2];
#pragma unroll
        for (int kh = 0; kh < 2; ++kh) {
            float4 a0 = *(const float4*)(pA + k0 + kh * 32 + lg * 8);
            float4 a1 = *(const float4*)(pA + k0 + kh * 32 + lg * 8 + 4);
            ushort* ap = (ushort*)&abf[kh];
            ap[0] = f2bf(a0.x); ap[1] = f2bf(a0.y); ap[2] = f2bf(a0.z); ap[3] = f2bf(a0.w);
            ap[4] = f2bf(a1.x); ap[5] = f2bf(a1.y); ap[6] = f2bf(a1.z); ap[7] = f2bf(a1.w);
        }
#pragma unroll
        for (int kh = 0; kh < 2; ++kh)
#pragma unroll
            for (int nf = 0; nf < 2; ++nf) {
                bf16x8 bfv = *(const bf16x8*)(WT + (size_t)(c0 + nf * 16 + lr) * IN_DIM + k0 + kh * 32 + lg * 8);
                acc[nf] = __builtin_amdgcn_mfma_f32_16x16x32_bf16(abf[kh], bfv, acc[nf], 0, 0, 0);
            }
    }

    const int m0 = r0 + lg * 4;           // rows m0..m0+3, 4-aligned, < 10000
#pragma unroll
    for (int nf = 0; nf < 2; ++nf) {
        int c = c0 + nf * 16 + lr;
        ushort4 pk;
        pk.x = f2bf(acc[nf][0]); pk.y = f2bf(acc[nf][1]);
        pk.z = f2bf(acc[nf][2]); pk.w = f2bf(acc[nf][3]);
        *(ushort4*)(hT + (size_t)c * HT_S + m0) = pk;
    }
}

// ---------------- kernel 2: zp[split] = adj @ h, BK=128 (R15/R18-proven) ----
__global__ __launch_bounds__(256) void k_adj(const float* __restrict__ adj,
                                             const ushort* __restrict__ hT,
                                             float* __restrict__ zp) {
    __shared__ ushort Bs[BN * BK];        // 32 KB

    const int tid = threadIdx.x, wave = tid >> 6, lane = tid & 63;
    const int lr = lane & 15, lg = lane >> 4;
    const int m0 = blockIdx.x * BM;
    const int split = blockIdx.y;
    const int step0 = split * STEPS_PER_SPLIT;
    const int step1 = min(step0 + STEPS_PER_SPLIT, KSTEPS_TOTAL);

    // B staging descriptors (loop-invariant): 2048 chunks of 16B
    long  bbase[8];
    char* bldst[8];
#pragma unroll
    for (int q = 0; q < 8; ++q) {
        int c = tid + q * 256;
        int row = c >> 4, ch = c & 15;
        bbase[q] = (long)row * HT_S + (long)((ch ^ (row & 15)) * 8);
        bldst[q] = (char*)Bs + c * 16;
    }

    // A row pointer (clamped; out-of-range rows' outputs are discarded)
    const int arow = min(m0 + wave * 16 + lr, N_NODES - 1);
    const float* pA = adj + (size_t)arow * K_DIM;

    f32x4 acc[8];
#pragma unroll
    for (int nf = 0; nf < 8; ++nf) acc[nf] = (f32x4){0.f, 0.f, 0.f, 0.f};

    const char* Bb = (const char*)Bs;

    for (int st = step0; st < step1; ++st) {
        const int k0 = st * BK;

        // stage B via async DMA (32 KB / block / step, hT is L2-resident)
#pragma unroll
        for (int q = 0; q < 8; ++q)
            gl2lds16(hT + (bbase[q] + k0), bldst[q]);

        // A direct to registers: 8 independent dwordx4 (clamped so k-overrun
        // lanes read in-bounds; their products hit B=0 pad rows)
        float4 fa[4][2];
#pragma unroll
        for (int kh = 0; kh < 4; ++kh) {
            int kk = k0 + kh * 32 + lg * 8;
            int kc = (kk <= K_DIM - 8) ? kk : (K_DIM - 8);
            fa[kh][0] = *(const float4*)(pA + kc);
            fa[kh][1] = *(const float4*)(pA + kc + 4);
        }

        __syncthreads();   // B tile visible (vmcnt0 also covers A regs)

#pragma unroll
        for (int kh = 0; kh < 4; ++kh) {
            bf16x8 abf;
            ushort* ap = (ushort*)&abf;
            const float* f0 = (const float*)&fa[kh][0];
#pragma unroll
            for (int e = 0; e < 8; ++e) ap[e] = f2bf(f0[e]);
#pragma unroll
            for (int nf = 0; nf < 8; ++nf) {
                int brow = nf * 16 + lr;
                bf16x8 bv = *(const bf16x8*)(Bb + brow * 256 + (((kh * 4 + lg) ^ (brow & 15)) * 16));
                acc[nf] = __builtin_amdgcn_mfma_f32_16x16x32_bf16(abf, bv, acc[nf], 0, 0, 0);
            }
        }

        __syncthreads();   // all B reads done before next-step overwrite
    }

    // epilogue: write split-partial z
    float* out = zp + (size_t)split * N_NODES * OUT_DIM;
    const int orow = m0 + wave * 16 + lg * 4;
#pragma unroll
    for (int nf = 0; nf < 8; ++nf)
#pragma unroll
        for (int r = 0; r < 4; ++r) {
            int row = orow + r;
            if (row < N_NODES)
                out[(size_t)row * OUT_DIM + nf * 16 + lr] = acc[nf][r];
        }
}

// ---------------- kernel 3: reduce splits + per-node precompute --------------
__global__ __launch_bounds__(256) void k_node(const float* __restrict__ zp,
                                              const float* __restrict__ v,
                                              float* __restrict__ a,
                                              float* __restrict__ b,
                                              ushort* __restrict__ zb) {
    const int wave = threadIdx.x >> 6, lane = threadIdx.x & 63;
    const int i = blockIdx.x * 4 + wave;
    if (i >= N_NODES) return;
    const int k0 = lane, k1 = lane + 64;

    float z0 = 0.f, z1 = 0.f;
#pragma unroll
    for (int s = 0; s < SPLITS; ++s) {
        const float* row = zp + ((size_t)s * N_NODES + i) * OUT_DIM;
        z0 += row[k0];
        z1 += row[k1];
    }
    zb[(size_t)i * OUT_DIM + k0] = f2bf(z0);
    zb[(size_t)i * OUT_DIM + k1] = f2bf(z1);

    float ra = fmaxf(z0, 0.f) * v[k0] + fmaxf(z1, 0.f) * v[k1];
    float rb = fmaxf(z0, 0.f) * v[OUT_DIM + k0] + fmaxf(z1, 0.f) * v[OUT_DIM + k1];
#pragma unroll
    for (int off = 32; off; off >>= 1) {
        ra += __shfl_down(ra, off);
        rb += __shfl_down(rb, off);
    }
    if (lane == 0) { a[i] = ra; b[i] = rb; }
}

// ---------------- kernel 4: per-edge logit + sigmoid (R15/R18-proven) --------
__global__ __launch_bounds__(256) void k_edge(const int* __restrict__ e_true,
                                              const int* __restrict__ e_false,
                                              const float* __restrict__ a,
                                              const float* __restrict__ b,
                                              const ushort* __restrict__ zb,
                                              const float* __restrict__ w3,
                                              float* __restrict__ out) {
    const int lane = threadIdx.x & 63;
    const int grp  = lane >> 4;            // 4 edge-slots per wave
    const int l16  = lane & 15;
    const int gw   = (blockIdx.x * blockDim.x + threadIdx.x) >> 6;
    const int nw   = (gridDim.x * blockDim.x) >> 6;

    const float4 wv0 = *(const float4*)(w3 + OUT_DIM + l16 * 8);
    const float4 wv1 = *(const float4*)(w3 + OUT_DIM + l16 * 8 + 4);

    for (int e4 = gw; e4 < (2 * NE) / 4; e4 += nw) {
        const int e = e4 * 4 + grp;
        int2 ij = (e < NE) ? ((const int2*)e_true)[e] : ((const int2*)e_false)[e - NE];
        const int i = ij.x, j = ij.y;

        uint4 zi = *(const uint4*)(zb + (size_t)i * OUT_DIM + l16 * 8);
        uint4 zj = *(const uint4*)(zb + (size_t)j * OUT_DIM + l16 * 8);

        float d;
        d  = wv0.x * bflo(zi.x) * bflo(zj.x);
        d += wv0.y * bfhi(zi.x) * bfhi(zj.x);
        d += wv0.z * bflo(zi.y) * bflo(zj.y);
        d += wv0.w * bfhi(zi.y) * bfhi(zj.y);
        d += wv1.x * bflo(zi.z) * bflo(zj.z);
        d += wv1.y * bfhi(zi.z) * bfhi(zj.z);
        d += wv1.z * bflo(zi.w) * bflo(zj.w);
        d += wv1.w * bfhi(zi.w) * bfhi(zj.w);

#pragma unroll
        for (int off = 8; off; off >>= 1) d += __shfl_xor(d, off, 64);
        if (l16 == 0) {
            float logit = a[i] + b[j] + d;
            out[e] = 1.0f / (1.0f + __expf(-logit));
        }
    }
}

// ---------------- launch ----------------
extern "C" void kernel_launch(void* const* d_in, const int* in_sizes, int n_in,
                              void* d_out, int out_size, void* d_ws, size_t ws_size,
                              hipStream_t stream) {
    const float* x      = (const float*)d_in[0];
    const float* adj    = (const float*)d_in[1];
    const float* w      = (const float*)d_in[2];
    const float* w2     = (const float*)d_in[3];
    const float* w3     = (const float*)d_in[4];
    const int* e_true   = (const int*)d_in[5];
    const int* e_false  = (const int*)d_in[6];
    float* out          = (float*)d_out;

    char* ws = (char*)d_ws;
    // workspace layout (bytes)
    ushort* hT  = (ushort*)(ws);                        //  2,588,672 (128 x 10112 bf16)
    float*  zp  = (float*)(ws + 2588672);               // 40,960,000 (8 x 10000 x 128 f32)
    float*  v   = (float*)(ws + 43548672);              //      1,024
    float*  a   = (float*)(ws + 43549696);              //     40,000
    float*  b   = (float*)(ws + 43589696);              //     40,000
    ushort* zb  = (ushort*)(ws + 43629696);             //  2,560,000 (bf16)
    ushort* WT  = (ushort*)(ws + 46189696);             //    131,072  -> ~46.3 MB

    k_prep<<<64, 256, 0, stream>>>(w, w2, w3, WT, v, hT);
    k_xw<<<625, 256, 0, stream>>>(x, WT, hT);
    k_adj<<<dim3(157, SPLITS), 256, 0, stream>>>(adj, hT, zp);
    k_node<<<2500, 256, 0, stream>>>(zp, v, a, b, zb);
    k_edge<<<2048, 256, 0, stream>>>(e_true, e_false, a, b, zb, w3, out);
}